// Round 1
// baseline (629.902 us; speedup 1.0000x reference)
//
#include <hip/hip_runtime.h>

// Causal MHA forward, B=4 H=16 S=2048 D=64, fp32 I/O, bf16 MFMA compute.
// R5: fused anti-diagonal pair + double-buffered K/V LDS + register prefetch.
//   - The pair (pr, 15-pr) is processed in ONE kv-tile loop: lo-block tiles are
//     a subset of hi-block tiles, so each K/V tile is staged once and consumed
//     by both q-blocks (staging passes 36 -> avg 25/WG, barriers 72 -> ~26).
//   - Pipeline: issue tile t+1 global loads into regs -> compute tile t from
//     LDS[cur] -> convert+write LDS[cur^1] -> ONE __syncthreads per tile.
//     Global latency hides under compute; barrier vmcnt drain is free because
//     prefetch regs are consumed pre-barrier.
// R4-proven math kept: no-max flash softmax (exp2, log2e folded into Q scale),
// denominator via all-ones MFMA (same C-layout as O), V^T stride 72 single
// ds_read_b128 fragments, per-wave P round-trip through LDS.

typedef float  f32x4  __attribute__((ext_vector_type(4)));
typedef short  bf16x8 __attribute__((ext_vector_type(8)));

#define NH      16
#define DH      64
#define SEQ     2048
#define NSTATE  1024
#define ROW3    3072
#define BQ      128
#define BK      64
#define NQB     (SEQ / BQ)      // 16 q-blocks
#define KST     72
#define VST     72
#define PST     72
#define NEG_BIG (-1e9f)
#define QSC     (0.125f * 1.4426950408889634f)   // 1/sqrt(64) * log2(e)

// pack two fp32 -> two RNE bf16 in one u32 (bfe+add3 each + v_perm)
static __device__ __forceinline__ unsigned pk2(float x, float y) {
    unsigned ux = __builtin_bit_cast(unsigned, x);
    unsigned uy = __builtin_bit_cast(unsigned, y);
    ux += 0x7FFFu + ((ux >> 16) & 1u);
    uy += 0x7FFFu + ((uy >> 16) & 1u);
    return __builtin_amdgcn_perm(uy, ux, 0x07060302u);   // [uy.hi16 : ux.hi16]
}

// ---- staging: issue global loads into regs (no wait) --------------------
#define ISSUE_STAGE(KV0)                                                       \
    {                                                                          \
        _Pragma("unroll")                                                      \
        for (int i = 0; i < 2; ++i) {                                          \
            int p  = tid + 512 * i;                                            \
            int kv = p >> 4;                                                   \
            int d  = (p & 15) * 4;                                             \
            kp[i] = *(const float4*)(kbase + (size_t)((KV0) + kv) * ROW3 + d); \
        }                                                                      \
        _Pragma("unroll")                                                      \
        for (int i = 0; i < 4; ++i) {                                          \
            int idx = tid + 512 * i;                                           \
            int d   = idx & 63;                                                \
            int kv  = (idx >> 6) * 2;                                          \
            const float* gp = vbase + (size_t)((KV0) + kv) * ROW3 + d;         \
            vp[2 * i]     = gp[0];                                             \
            vp[2 * i + 1] = gp[ROW3];                                          \
        }                                                                      \
    }

// ---- staging: convert prefetched regs -> bf16 LDS tile ------------------
#define COMMIT_STAGE(BUF)                                                      \
    {                                                                          \
        _Pragma("unroll")                                                      \
        for (int i = 0; i < 2; ++i) {                                          \
            int p  = tid + 512 * i;                                            \
            int kv = p >> 4;                                                   \
            int d  = (p & 15) * 4;                                             \
            uint2 w;                                                           \
            w.x = pk2(kp[i].x, kp[i].y);                                       \
            w.y = pk2(kp[i].z, kp[i].w);                                       \
            *(uint2*)&Klds[BUF][kv * KST + d] = w;                             \
        }                                                                      \
        _Pragma("unroll")                                                      \
        for (int i = 0; i < 4; ++i) {                                          \
            int idx = tid + 512 * i;                                           \
            int d   = idx & 63;                                                \
            int kv  = (idx >> 6) * 2;                                          \
            *(unsigned*)&Vlds[BUF][d * VST + kv] = pk2(vp[2 * i], vp[2 * i + 1]); \
        }                                                                      \
    }

// ---- Q fragment (B-operand of S^T = K*Q^T), scaled by QSC ---------------
#define LOAD_Q(Q0, QF)                                                         \
    {                                                                          \
        const int qrow_ = (Q0) + wave * 16 + l16;                              \
        const float* qp = xb + (size_t)qrow_ * ROW3 + h * DH + quad * 8;       \
        _Pragma("unroll")                                                      \
        for (int f = 0; f < 2; ++f) {                                          \
            float4 a = *(const float4*)(qp + 32 * f);                          \
            float4 c = *(const float4*)(qp + 32 * f + 4);                      \
            union { bf16x8 v; unsigned u[4]; } qq;                             \
            qq.u[0] = pk2(a.x * QSC, a.y * QSC);                               \
            qq.u[1] = pk2(a.z * QSC, a.w * QSC);                               \
            qq.u[2] = pk2(c.x * QSC, c.y * QSC);                               \
            qq.u[3] = pk2(c.z * QSC, c.w * QSC);                               \
            QF[f] = qq.v;                                                      \
        }                                                                      \
    }

// ---- one q-block's work against the current K/V tile --------------------
#define COMPUTE_BLOCK(Q0, QF, OACC, OL)                                        \
    {                                                                          \
        const int qmin_ = (Q0) + wave * 16;                                    \
        if (kv0 <= qmin_ + 15) {                                               \
            const int qrow_ = qmin_ + l16;                                     \
            f32x4 sc[4];                                                       \
            _Pragma("unroll")                                                  \
            for (int t = 0; t < 4; ++t) {                                      \
                f32x4 c = (f32x4){0.f, 0.f, 0.f, 0.f};                         \
                c = __builtin_amdgcn_mfma_f32_16x16x32_bf16(kf[t][0], QF[0], c, 0, 0, 0); \
                c = __builtin_amdgcn_mfma_f32_16x16x32_bf16(kf[t][1], QF[1], c, 0, 0, 0); \
                sc[t] = c;                                                     \
            }                                                                  \
            if (kv0 + BK - 1 > qmin_) {                                        \
                _Pragma("unroll")                                              \
                for (int t = 0; t < 4; ++t)                                    \
                    _Pragma("unroll")                                          \
                    for (int r = 0; r < 4; ++r) {                              \
                        int kvg = kv0 + 16 * t + 4 * quad + r;                 \
                        if (kvg > qrow_) sc[t][r] = NEG_BIG;                   \
                    }                                                          \
            }                                                                  \
            _Pragma("unroll")                                                  \
            for (int t = 0; t < 4; ++t)                                        \
                _Pragma("unroll")                                              \
                for (int r = 0; r < 4; ++r)                                    \
                    sc[t][r] = __builtin_amdgcn_exp2f(sc[t][r]);               \
            short* pb = &Plds[wave][0];                                        \
            _Pragma("unroll")                                                  \
            for (int t = 0; t < 4; ++t) {                                      \
                uint2 pk;                                                      \
                pk.x = pk2(sc[t][0], sc[t][1]);                                \
                pk.y = pk2(sc[t][2], sc[t][3]);                                \
                *(uint2*)&pb[l16 * PST + 16 * t + 4 * quad] = pk;              \
            }                                                                  \
            __asm__ volatile("s_waitcnt lgkmcnt(0)" ::: "memory");             \
            bf16x8 pf0 = *(const bf16x8*)&pb[l16 * PST + quad * 8];            \
            bf16x8 pf1 = *(const bf16x8*)&pb[l16 * PST + quad * 8 + 32];       \
            _Pragma("unroll")                                                  \
            for (int t = 0; t < 4; ++t) {                                      \
                f32x4 c = OACC[t];                                             \
                c = __builtin_amdgcn_mfma_f32_16x16x32_bf16(pf0, vf[t][0], c, 0, 0, 0); \
                c = __builtin_amdgcn_mfma_f32_16x16x32_bf16(pf1, vf[t][1], c, 0, 0, 0); \
                OACC[t] = c;                                                   \
            }                                                                  \
            OL = __builtin_amdgcn_mfma_f32_16x16x32_bf16(pf0, vones, OL, 0, 0, 0); \
            OL = __builtin_amdgcn_mfma_f32_16x16x32_bf16(pf1, vones, OL, 0, 0, 0); \
        }                                                                      \
    }

#define EPILOGUE(Q0, OACC, OL)                                                 \
    {                                                                          \
        const int qtop_ = (Q0) + wave * 16 + 4 * quad;                         \
        float lr[4];                                                           \
        _Pragma("unroll")                                                      \
        for (int r = 0; r < 4; ++r) lr[r] = 1.0f / OL[r];                      \
        _Pragma("unroll")                                                      \
        for (int t = 0; t < 4; ++t)                                            \
            _Pragma("unroll")                                                  \
            for (int r = 0; r < 4; ++r)                                        \
                ob[(size_t)(qtop_ + r) * NSTATE + 16 * t + l16] = OACC[t][r] * lr[r]; \
    }

__global__ __launch_bounds__(512, 4)
void mha_fwd(const float* __restrict__ x, float* __restrict__ out) {
    const int tid  = threadIdx.x;
    const int wave = tid >> 6;        // 0..7  (one 16-row strip per q-block)
    const int lane = tid & 63;
    const int l16  = lane & 15;
    const int quad = lane >> 4;

    const int pr = blockIdx.x;        // pair index 0..7
    const int bh = blockIdx.y;
    const int b  = bh >> 4;
    const int h  = bh & 15;

    const float* xb    = x + (size_t)b * SEQ * ROW3;
    const float* kbase = xb + NSTATE + h * DH;
    const float* vbase = xb + 2 * NSTATE + h * DH;
    float*       ob    = out + (size_t)b * SEQ * NSTATE + h * DH;

    __shared__ __align__(16) short Klds[2][BK * KST];    // double-buffered K[kv][d]
    __shared__ __align__(16) short Vlds[2][DH * VST];    // double-buffered V^T[d][kv]
    __shared__ __align__(16) short Plds[8][16 * PST];    // per-wave P[q][kv]

    const int q0_lo = pr * BQ;                  // lo q-block of the pair
    const int q0_hi = (NQB - 1 - pr) * BQ;      // hi q-block of the pair
    const int ntl   = q0_lo / BK + 2;           // tiles needed by lo block
    const int nt    = q0_hi / BK + 2;           // tiles staged (hi covers lo)

    // all-ones bf16 B-fragment for the denominator MFMA (no LDS needed)
    bf16x8 vones;
#pragma unroll
    for (int i = 0; i < 8; ++i) vones[i] = (short)0x3F80;

    // Q fragments for both q-blocks, loaded once
    bf16x8 qlo[2], qhi[2];
    LOAD_Q(q0_lo, qlo)
    LOAD_Q(q0_hi, qhi)

    f32x4 o_lo[4], o_hi[4];
#pragma unroll
    for (int t = 0; t < 4; ++t) {
        o_lo[t] = (f32x4){0.f, 0.f, 0.f, 0.f};
        o_hi[t] = (f32x4){0.f, 0.f, 0.f, 0.f};
    }
    f32x4 d_lo = (f32x4){0.f, 0.f, 0.f, 0.f};
    f32x4 d_hi = (f32x4){0.f, 0.f, 0.f, 0.f};

    // prefetch registers
    float4 kp[2];
    float  vp[8];

    // prologue: stage tile 0 into buffer 0
    ISSUE_STAGE(0)
    COMMIT_STAGE(0)
    __syncthreads();

#pragma unroll 1
    for (int it = 0; it < nt; ++it) {
        const int kv0 = it * BK;
        const int cur = it & 1;
        const bool pf = (it + 1 < nt);

        // issue next tile's global loads early; latency hides under compute
        if (pf) ISSUE_STAGE((it + 1) * BK)

        // K fragments (A-operand): K[16t+l16][8quad+32f+j]
        bf16x8 kf[4][2];
#pragma unroll
        for (int t = 0; t < 4; ++t)
#pragma unroll
            for (int f = 0; f < 2; ++f)
                kf[t][f] = *(const bf16x8*)&Klds[cur][(16 * t + l16) * KST + quad * 8 + 32 * f];
        // V fragments (B-operand) from V^T: single b128 each
        bf16x8 vf[4][2];
#pragma unroll
        for (int t = 0; t < 4; ++t)
#pragma unroll
            for (int f = 0; f < 2; ++f)
                vf[t][f] = *(const bf16x8*)&Vlds[cur][(16 * t + l16) * VST + quad * 8 + 32 * f];

        if (it < ntl) COMPUTE_BLOCK(q0_lo, qlo, o_lo, d_lo)
        COMPUTE_BLOCK(q0_hi, qhi, o_hi, d_hi)

        // convert + write next tile into the other buffer, then ONE barrier
        if (pf) COMMIT_STAGE(cur ^ 1)
        __syncthreads();
    }

    EPILOGUE(q0_lo, o_lo, d_lo)
    EPILOGUE(q0_hi, o_hi, d_hi)
}

extern "C" void kernel_launch(void* const* d_in, const int* in_sizes, int n_in,
                              void* d_out, int out_size, void* d_ws, size_t ws_size,
                              hipStream_t stream) {
    const float* x = (const float*)d_in[0];   // [B,S,3*NSTATE] fp32
    // d_in[1] (attn_mask) is not read: the mask is causal and computed inline.
    float* out = (float*)d_out;               // [B,S,NSTATE] fp32
    dim3 grid(NQB / 2, 4 * NH);               // 8 pairs x 64 (b,h)
    dim3 block(512);
    hipLaunchKernelGGL(mha_fwd, grid, block, 0, stream, x, out);
}

// Round 2
// 252.688 us; speedup vs baseline: 2.4928x; 2.4928x over previous
//
#include <hip/hip_runtime.h>

// Causal MHA forward, B=4 H=16 S=2048 D=64, fp32 I/O, bf16 MFMA compute.
// R6: R4 skeleton (two sequential anti-diagonal phases, ONE q-block live ->
// 56-VGPR-class footprint, no spill) + per-phase double-buffered K/V LDS with
// register prefetch: issue tile t+1 fp32 loads -> compute tile t -> convert+
// write LDS[t+1] -> ONE barrier.  R5's pair-fusion is reverted: holding two
// q-blocks' accumulators + fragments + prefetch exceeded the 128-VGPR cap and
// spilled ~690 MB/dispatch to scratch (WRITE_SIZE 33->721 MB, 4x regression).
// R4-proven math kept: no-max flash softmax (exp2, log2e folded into Q scale),
// denominator via all-ones MFMA (same C-layout as O), V^T stride 72 single
// ds_read_b128 fragments, per-wave P round-trip through LDS.

typedef float  f32x4  __attribute__((ext_vector_type(4)));
typedef short  bf16x8 __attribute__((ext_vector_type(8)));

#define NH      16
#define DH      64
#define SEQ     2048
#define NSTATE  1024
#define ROW3    3072
#define BQ      128
#define BK      64
#define NQB     (SEQ / BQ)      // 16 q-blocks
#define KST     72
#define VST     72
#define PST     72
#define NEG_BIG (-1e9f)
#define QSC     (0.125f * 1.4426950408889634f)   // 1/sqrt(64) * log2(e)

// pack two fp32 -> two RNE bf16 in one u32 (bfe+add3 each + v_perm)
static __device__ __forceinline__ unsigned pk2(float x, float y) {
    unsigned ux = __builtin_bit_cast(unsigned, x);
    unsigned uy = __builtin_bit_cast(unsigned, y);
    ux += 0x7FFFu + ((ux >> 16) & 1u);
    uy += 0x7FFFu + ((uy >> 16) & 1u);
    return __builtin_amdgcn_perm(uy, ux, 0x07060302u);   // [uy.hi16 : ux.hi16]
}

// ---- staging: issue global loads into regs (no wait) --------------------
#define ISSUE_STAGE(KV0)                                                       \
    {                                                                          \
        _Pragma("unroll")                                                      \
        for (int i = 0; i < 2; ++i) {                                          \
            int p  = tid + 512 * i;                                            \
            int kv = p >> 4;                                                   \
            int d  = (p & 15) * 4;                                             \
            kp[i] = *(const float4*)(kbase + (size_t)((KV0) + kv) * ROW3 + d); \
        }                                                                      \
        _Pragma("unroll")                                                      \
        for (int i = 0; i < 4; ++i) {                                          \
            int idx = tid + 512 * i;                                           \
            int d   = idx & 63;                                                \
            int kv  = (idx >> 6) * 2;                                          \
            const float* gp = vbase + (size_t)((KV0) + kv) * ROW3 + d;         \
            vp[2 * i]     = gp[0];                                             \
            vp[2 * i + 1] = gp[ROW3];                                          \
        }                                                                      \
    }

// ---- staging: convert prefetched regs -> bf16 LDS tile ------------------
#define COMMIT_STAGE(BUF)                                                      \
    {                                                                          \
        _Pragma("unroll")                                                      \
        for (int i = 0; i < 2; ++i) {                                          \
            int p  = tid + 512 * i;                                            \
            int kv = p >> 4;                                                   \
            int d  = (p & 15) * 4;                                             \
            uint2 w;                                                           \
            w.x = pk2(kp[i].x, kp[i].y);                                       \
            w.y = pk2(kp[i].z, kp[i].w);                                       \
            *(uint2*)&Klds[BUF][kv * KST + d] = w;                             \
        }                                                                      \
        _Pragma("unroll")                                                      \
        for (int i = 0; i < 4; ++i) {                                          \
            int idx = tid + 512 * i;                                           \
            int d   = idx & 63;                                                \
            int kv  = (idx >> 6) * 2;                                          \
            *(unsigned*)&Vlds[BUF][d * VST + kv] = pk2(vp[2 * i], vp[2 * i + 1]); \
        }                                                                      \
    }

__global__ __launch_bounds__(512, 4)
void mha_fwd(const float* __restrict__ x, float* __restrict__ out) {
    const int tid  = threadIdx.x;
    const int wave = tid >> 6;        // 0..7  (one 16-row strip each)
    const int lane = tid & 63;
    const int l16  = lane & 15;
    const int quad = lane >> 4;

    const int pr = blockIdx.x;        // pair index 0..7
    const int bh = blockIdx.y;
    const int b  = bh >> 4;
    const int h  = bh & 15;

    const float* xb    = x + (size_t)b * SEQ * ROW3;
    const float* kbase = xb + NSTATE + h * DH;
    const float* vbase = xb + 2 * NSTATE + h * DH;
    float*       ob    = out + (size_t)b * SEQ * NSTATE + h * DH;

    __shared__ __align__(16) short Klds[2][BK * KST];    // double-buffered K[kv][d]
    __shared__ __align__(16) short Vlds[2][DH * VST];    // double-buffered V^T[d][kv]
    __shared__ __align__(16) short Plds[8][16 * PST];    // per-wave P[q][kv]

    // all-ones bf16 B-fragment for the denominator MFMA (no LDS needed)
    bf16x8 vones;
#pragma unroll
    for (int i = 0; i < 8; ++i) vones[i] = (short)0x3F80;

    // prefetch registers (live across one compute tile only)
    float4 kp[2];
    float  vp[8];

#pragma unroll 1
    for (int ph = 0; ph < 2; ++ph) {
        const int qblk = ph ? (NQB - 1 - pr) : pr;   // pair (i, 15-i): 34 tiles total
        const int q0   = qblk * BQ;
        const int qmin = q0 + wave * 16;             // this wave's strip
        const int qrow = qmin + l16;                 // this lane's softmax row

        // ---- Q fragment (B-operand of S^T = K*Q^T), scaled by QSC ----
        bf16x8 qf[2];
        {
            const float* qp = xb + (size_t)qrow * ROW3 + h * DH + quad * 8;
#pragma unroll
            for (int f = 0; f < 2; ++f) {
                float4 a = *(const float4*)(qp + 32 * f);
                float4 c = *(const float4*)(qp + 32 * f + 4);
                union { bf16x8 v; unsigned u[4]; } qq;
                qq.u[0] = pk2(a.x * QSC, a.y * QSC);
                qq.u[1] = pk2(a.z * QSC, a.w * QSC);
                qq.u[2] = pk2(c.x * QSC, c.y * QSC);
                qq.u[3] = pk2(c.z * QSC, c.w * QSC);
                qf[f] = qq.v;
            }
        }

        f32x4 o[4];
#pragma unroll
        for (int t = 0; t < 4; ++t) o[t] = (f32x4){0.f, 0.f, 0.f, 0.f};
        f32x4 ol = (f32x4){0.f, 0.f, 0.f, 0.f};      // softmax denominator

        const int ntiles = q0 / BK + BQ / BK;

        // ---- prologue: stage tile 0 into buffer 0 ----
        __syncthreads();                 // protect LDS reuse from previous phase
        ISSUE_STAGE(0)
        COMMIT_STAGE(0)
        __syncthreads();

#pragma unroll 1
        for (int it = 0; it < ntiles; ++it) {
            const int kv0 = it * BK;
            const int cur = it & 1;
            const bool pf = (it + 1 < ntiles);

            // issue next tile's global loads early; latency hides under compute
            if (pf) ISSUE_STAGE((it + 1) * BK)

            if (kv0 <= qmin + 15) {      // strip not fully masked (wave-uniform)
                // ---- K fragments (A-operand): K[16t+l16][8quad+32f+j] ----
                bf16x8 kf[4][2];
#pragma unroll
                for (int t = 0; t < 4; ++t)
#pragma unroll
                    for (int f = 0; f < 2; ++f)
                        kf[t][f] = *(const bf16x8*)&Klds[cur][(16 * t + l16) * KST + quad * 8 + 32 * f];
                // ---- V fragments (B-operand) from V^T: single b128 each ----
                bf16x8 vf[4][2];
#pragma unroll
                for (int t = 0; t < 4; ++t)
#pragma unroll
                    for (int f = 0; f < 2; ++f)
                        vf[t][f] = *(const bf16x8*)&Vlds[cur][(16 * t + l16) * VST + quad * 8 + 32 * f];

                // S^T tiles: St[kv = 16t+4*quad+r][q = l16], log2e domain
                f32x4 sc[4];
#pragma unroll
                for (int t = 0; t < 4; ++t) {
                    f32x4 c = (f32x4){0.f, 0.f, 0.f, 0.f};
                    c = __builtin_amdgcn_mfma_f32_16x16x32_bf16(kf[t][0], qf[0], c, 0, 0, 0);
                    c = __builtin_amdgcn_mfma_f32_16x16x32_bf16(kf[t][1], qf[1], c, 0, 0, 0);
                    sc[t] = c;
                }
                if (kv0 + BK - 1 > qmin) {          // tile may cross the diagonal
#pragma unroll
                    for (int t = 0; t < 4; ++t)
#pragma unroll
                        for (int r = 0; r < 4; ++r) {
                            int kvg = kv0 + 16 * t + 4 * quad + r;
                            if (kvg > qrow) sc[t][r] = NEG_BIG;
                        }
                }

                // no-max softmax numerator: p = exp2(s)  (v_exp_f32, 0 for masked)
#pragma unroll
                for (int t = 0; t < 4; ++t)
#pragma unroll
                    for (int r = 0; r < 4; ++r)
                        sc[t][r] = __builtin_amdgcn_exp2f(sc[t][r]);

                // P[q=l16][kv=16t+4*quad+r] -> LDS (b64 writes)
                short* pb = &Plds[wave][0];
#pragma unroll
                for (int t = 0; t < 4; ++t) {
                    uint2 pk;
                    pk.x = pk2(sc[t][0], sc[t][1]);
                    pk.y = pk2(sc[t][2], sc[t][3]);
                    *(uint2*)&pb[l16 * PST + 16 * t + 4 * quad] = pk;
                }
                __asm__ volatile("s_waitcnt lgkmcnt(0)" ::: "memory");
                bf16x8 pf0 = *(const bf16x8*)&pb[l16 * PST + quad * 8];
                bf16x8 pf1 = *(const bf16x8*)&pb[l16 * PST + quad * 8 + 32];

                // O += P*V ; denominator += P*ones (same C-layout as O rows)
#pragma unroll
                for (int t = 0; t < 4; ++t) {
                    f32x4 c = o[t];
                    c = __builtin_amdgcn_mfma_f32_16x16x32_bf16(pf0, vf[t][0], c, 0, 0, 0);
                    c = __builtin_amdgcn_mfma_f32_16x16x32_bf16(pf1, vf[t][1], c, 0, 0, 0);
                    o[t] = c;
                }
                ol = __builtin_amdgcn_mfma_f32_16x16x32_bf16(pf0, vones, ol, 0, 0, 0);
                ol = __builtin_amdgcn_mfma_f32_16x16x32_bf16(pf1, vones, ol, 0, 0, 0);
            }

            // convert + write next tile into the other buffer, then ONE barrier
            if (pf) COMMIT_STAGE(cur ^ 1)
            __syncthreads();
        }

        // ---- epilogue: O /= l (denominator already in matching rows) ----
        {
            const int qtop = qmin + 4 * quad;
            float lr[4];
#pragma unroll
            for (int r = 0; r < 4; ++r) lr[r] = 1.0f / ol[r];
#pragma unroll
            for (int t = 0; t < 4; ++t)
#pragma unroll
                for (int r = 0; r < 4; ++r)
                    ob[(size_t)(qtop + r) * NSTATE + 16 * t + l16] = o[t][r] * lr[r];
        }
    }
}

extern "C" void kernel_launch(void* const* d_in, const int* in_sizes, int n_in,
                              void* d_out, int out_size, void* d_ws, size_t ws_size,
                              hipStream_t stream) {
    const float* x = (const float*)d_in[0];   // [B,S,3*NSTATE] fp32
    // d_in[1] (attn_mask) is not read: the mask is causal and computed inline.
    float* out = (float*)d_out;               // [B,S,NSTATE] fp32
    dim3 grid(NQB / 2, 4 * NH);               // 8 pairs x 64 (b,h)
    dim3 block(512);
    hipLaunchKernelGGL(mha_fwd, grid, block, 0, stream, x, out);
}

// Round 3
// 219.081 us; speedup vs baseline: 2.8752x; 1.1534x over previous
//
#include <hip/hip_runtime.h>

// Causal MHA forward, B=4 H=16 S=2048 D=64, fp32 I/O, bf16 MFMA compute.
// R7: 32x32x16 MFMA restructure. R6 counters showed LDS-pipe saturation
// (16 waves x ~235 LDS-cycles vs ~4000-cycle tile wall): every wave read the
// whole K/V tile with 16x16 fragments.  Changes:
//   - mfma_f32_32x32x16_bf16, 8 waves x 32-row q strips (BQ=256): LDS read
//     bytes per FLOP halve (16B fragment feeds 32K FLOP instead of 16K).
//   - P stays IN REGISTER: S^T = K*Q^T has q in the lane dim; per 16-kv chunk,
//     pack to bf16 (pk2) + 2x v_permlane32_swap_b32 builds the PV A-fragment
//     (T12 pattern).  Plds eliminated -> conflicts and ~60 LDS-cyc/wave-tile.
//   - denominator: in-lane tree sum of exp2(S^T) + one epilogue permlane swap
//     (cross-half) + ds_bpermute transpose of 1/l to O's row layout.
//   - grid 256 WGs (4 anti-diag pairs x 64 bh), 1D: bid%8==bh%8 -> all 4
//     pair-WGs of one (b,h) share an XCD L2 (K/V re-read becomes L2 hit).
//   - V staging remapped (d = tid&15 + 16i, kv = 2*(tid>>4)): LDS b32 writes
//     land 2-way (free) instead of 8-way.
// Kept from R6: double-buffered K/V LDS + register prefetch (one barrier per
// tile), no-max flash softmax (exp2, log2e folded into Q scale), stride-72
// conflict-even K/V layouts, fp32->bf16 pk2 staging.

typedef float  f32x4   __attribute__((ext_vector_type(4)));
typedef float  f32x16  __attribute__((ext_vector_type(16)));
typedef short  bf16x8  __attribute__((ext_vector_type(8)));

#define NH      16
#define DH      64
#define SEQ     2048
#define NSTATE  1024
#define ROW3    3072
#define BQ      256
#define BK      64
#define NQB     (SEQ / BQ)      // 8 q-blocks of 256
#define KST     72
#define VST     72
#define NEG_BIG (-1e9f)
#define QSC     (0.125f * 1.4426950408889634f)   // 1/sqrt(64) * log2(e)

// pack two fp32 -> two RNE bf16 in one u32
static __device__ __forceinline__ unsigned pk2(float x, float y) {
    unsigned ux = __builtin_bit_cast(unsigned, x);
    unsigned uy = __builtin_bit_cast(unsigned, y);
    ux += 0x7FFFu + ((ux >> 16) & 1u);
    uy += 0x7FFFu + ((uy >> 16) & 1u);
    return __builtin_amdgcn_perm(uy, ux, 0x07060302u);   // [uy.hi16 : ux.hi16]
}

// ---- staging: issue global loads into regs (no wait) --------------------
// K: 64kv x 64d fp32, thread slots kv=idx>>4, d=4*(idx&15), 2 iters.
// V: column pairs: d=(tid&15)+16i, kv=2*(tid>>4), 4 iters (2 loads each).
#define ISSUE_STAGE(KV0)                                                       \
    {                                                                          \
        _Pragma("unroll")                                                      \
        for (int i = 0; i < 2; ++i) {                                          \
            int p  = tid + 512 * i;                                            \
            int kv = p >> 4;                                                   \
            int d  = (p & 15) * 4;                                             \
            kp[i] = *(const f32x4*)(kbase + (size_t)((KV0) + kv) * ROW3 + d);  \
        }                                                                      \
        _Pragma("unroll")                                                      \
        for (int i = 0; i < 4; ++i) {                                          \
            int d  = (tid & 15) + 16 * i;                                      \
            int kv = (tid >> 4) * 2;                                           \
            const float* gp = vbase + (size_t)((KV0) + kv) * ROW3 + d;         \
            vp[2 * i]     = gp[0];                                             \
            vp[2 * i + 1] = gp[ROW3];                                          \
        }                                                                      \
    }

#define COMMIT_STAGE(BUF)                                                      \
    {                                                                          \
        _Pragma("unroll")                                                      \
        for (int i = 0; i < 2; ++i) {                                          \
            int p  = tid + 512 * i;                                            \
            int kv = p >> 4;                                                   \
            int d  = (p & 15) * 4;                                             \
            uint2 w;                                                           \
            w.x = pk2(kp[i][0], kp[i][1]);                                     \
            w.y = pk2(kp[i][2], kp[i][3]);                                     \
            *(uint2*)&Klds[BUF][kv * KST + d] = w;                             \
        }                                                                      \
        _Pragma("unroll")                                                      \
        for (int i = 0; i < 4; ++i) {                                          \
            int d  = (tid & 15) + 16 * i;                                      \
            int kv = (tid >> 4) * 2;                                           \
            *(unsigned*)&Vlds[BUF][d * VST + kv] = pk2(vp[2 * i], vp[2 * i + 1]); \
        }                                                                      \
    }

__global__ __launch_bounds__(512, 2)
void mha_fwd(const float* __restrict__ x, float* __restrict__ out) {
    const int tid  = threadIdx.x;
    const int wave = tid >> 6;        // 0..7 : one 32-row q strip each
    const int lane = tid & 63;
    const int r31  = lane & 31;       // MFMA row/col lane index
    const int hl   = lane >> 5;       // lane half

    const int bid = blockIdx.x;       // 0..255 ; bid%8 == bh%8 -> XCD co-location
    const int pr  = bid >> 6;         // pair index 0..3
    const int bh  = bid & 63;
    const int b   = bh >> 4;
    const int h   = bh & 15;

    const float* xb    = x + (size_t)b * SEQ * ROW3;
    const float* kbase = xb + NSTATE + h * DH;
    const float* vbase = xb + 2 * NSTATE + h * DH;
    float*       ob    = out + (size_t)b * SEQ * NSTATE + h * DH;

    __shared__ __align__(16) short Klds[2][BK * KST];    // K[kv][d]   bf16, dbuf
    __shared__ __align__(16) short Vlds[2][DH * VST];    // V^T[d][kv] bf16, dbuf

    // prefetch registers
    f32x4 kp[2];
    float vp[8];

#pragma unroll 1
    for (int ph = 0; ph < 2; ++ph) {
        const int qblk   = ph ? (NQB - 1 - pr) : pr;     // pair (i, 7-i): 36 tiles
        const int q0     = qblk * BQ;
        const int qstrip = q0 + wave * 32;
        const int qrow   = qstrip + r31;                 // this lane's q (col of S^T)

        // ---- Q fragments (B-operand of S^T), 4 k-chunks, scaled by QSC ----
        bf16x8 qf[4];
        {
            const float* qp = xb + (size_t)qrow * ROW3 + h * DH + hl * 8;
#pragma unroll
            for (int kc = 0; kc < 4; ++kc) {
                f32x4 a = *(const f32x4*)(qp + 16 * kc);
                f32x4 c = *(const f32x4*)(qp + 16 * kc + 4);
                union { bf16x8 v; unsigned u[4]; } qq;
                qq.u[0] = pk2(a[0] * QSC, a[1] * QSC);
                qq.u[1] = pk2(a[2] * QSC, a[3] * QSC);
                qq.u[2] = pk2(c[0] * QSC, c[1] * QSC);
                qq.u[3] = pk2(c[2] * QSC, c[3] * QSC);
                qf[kc] = qq.v;
            }
        }

        f32x16 o0, o1;                 // O[q 32][d 0..31], [d 32..63]
#pragma unroll
        for (int r = 0; r < 16; ++r) { o0[r] = 0.f; o1[r] = 0.f; }
        float dl = 0.f;                // per-lane softmax denominator (q = r31)

        const int ntiles = q0 / BK + BQ / BK;

        __syncthreads();               // protect LDS reuse from previous phase
        ISSUE_STAGE(0)
        COMMIT_STAGE(0)
        __syncthreads();

#pragma unroll 1
        for (int it = 0; it < ntiles; ++it) {
            const int kv0 = it * BK;
            const int cur = it & 1;
            const bool pf = (it + 1 < ntiles);

            if (pf) ISSUE_STAGE((it + 1) * BK)

            if (kv0 <= qstrip + 31) {          // strip not fully masked
#pragma unroll
                for (int H = 0; H < 2; ++H) {  // two 32-kv halves
                    const int kvb = kv0 + 32 * H;
                    if (kvb <= qstrip + 31) {  // half not fully masked (uniform)
                        // K fragments (A): row kv = r31, k = 16kc + 8hl + j
                        bf16x8 kf[4];
#pragma unroll
                        for (int kc = 0; kc < 4; ++kc)
                            kf[kc] = *(const bf16x8*)&Klds[cur][(32 * H + r31) * KST + 16 * kc + 8 * hl];

                        // S^T half tile: 32kv x 32q, accumulated over k
                        f32x16 s;
#pragma unroll
                        for (int r = 0; r < 16; ++r) s[r] = 0.f;
#pragma unroll
                        for (int kc = 0; kc < 4; ++kc)
                            s = __builtin_amdgcn_mfma_f32_32x32x16_bf16(kf[kc], qf[kc], s, 0, 0, 0);

                        if (kvb + 31 > qstrip) {          // crosses diagonal
#pragma unroll
                            for (int r = 0; r < 16; ++r) {
                                int kvg = kvb + (r & 3) + 8 * (r >> 2) + 4 * hl;
                                if (kvg > qrow) s[r] = NEG_BIG;
                            }
                        }
#pragma unroll
                        for (int r = 0; r < 16; ++r)
                            s[r] = __builtin_amdgcn_exp2f(s[r]);

                        // denominator: tree sum (masked elems are 0)
                        {
                            float a0 = (s[0] + s[1]) + (s[2] + s[3]);
                            float a1 = (s[4] + s[5]) + (s[6] + s[7]);
                            float a2 = (s[8] + s[9]) + (s[10] + s[11]);
                            float a3 = (s[12] + s[13]) + (s[14] + s[15]);
                            dl += (a0 + a1) + (a2 + a3);
                        }

                        // P -> bf16 A-fragments in-register (2 chunks of 16 kv)
#pragma unroll
                        for (int cc = 0; cc < 2; ++cc) {
                            unsigned wA = pk2(s[8 * cc + 0], s[8 * cc + 1]);
                            unsigned wB = pk2(s[8 * cc + 2], s[8 * cc + 3]);
                            unsigned wC = pk2(s[8 * cc + 4], s[8 * cc + 5]);
                            unsigned wD = pk2(s[8 * cc + 6], s[8 * cc + 7]);
                            // swap hi-lanes of first with lo-lanes of second:
                            // (wA,wC) -> (j01, j45); (wB,wD) -> (j23, j67)
                            __asm__ volatile("v_permlane32_swap_b32 %0, %1"
                                             : "+v"(wA), "+v"(wC));
                            __asm__ volatile("v_permlane32_swap_b32 %0, %1"
                                             : "+v"(wB), "+v"(wD));
                            union { bf16x8 v; unsigned u[4]; } pa;
                            pa.u[0] = wA; pa.u[1] = wB; pa.u[2] = wC; pa.u[3] = wD;

                            const int c = 2 * H + cc;     // global kv chunk
                            bf16x8 vf0 = *(const bf16x8*)&Vlds[cur][(r31)      * VST + 16 * c + 8 * hl];
                            bf16x8 vf1 = *(const bf16x8*)&Vlds[cur][(32 + r31) * VST + 16 * c + 8 * hl];
                            o0 = __builtin_amdgcn_mfma_f32_32x32x16_bf16(pa.v, vf0, o0, 0, 0, 0);
                            o1 = __builtin_amdgcn_mfma_f32_32x32x16_bf16(pa.v, vf1, o1, 0, 0, 0);
                        }
                    }
                }
            }

            if (pf) COMMIT_STAGE(cur ^ 1)
            __syncthreads();
        }

        // ---- epilogue ----
        // cross-half denominator: dl_total(q) = dl[lane q] + dl[lane q^32]
        {
            unsigned da = __builtin_bit_cast(unsigned, dl);
            unsigned db = da;
            __asm__ volatile("v_permlane32_swap_b32 %0, %1" : "+v"(da), "+v"(db));
            float dtot = __builtin_bit_cast(float, da) + __builtin_bit_cast(float, db);
            float rcp  = 1.0f / dtot;              // valid in all lanes for q=r31
#pragma unroll
            for (int r = 0; r < 16; ++r) {
                int srcq = (r & 3) + 8 * (r >> 2) + 4 * hl;   // O row for reg r
                float lr = __builtin_bit_cast(float,
                    __builtin_amdgcn_ds_bpermute(srcq << 2,
                        __builtin_bit_cast(int, rcp)));
                const size_t row = (size_t)(qstrip + srcq) * NSTATE;
                ob[row + r31]      = o0[r] * lr;
                ob[row + 32 + r31] = o1[r] * lr;
            }
        }
    }
}

extern "C" void kernel_launch(void* const* d_in, const int* in_sizes, int n_in,
                              void* d_out, int out_size, void* d_ws, size_t ws_size,
                              hipStream_t stream) {
    const float* x = (const float*)d_in[0];   // [B,S,3*NSTATE] fp32
    // d_in[1] (attn_mask) is not read: the mask is causal and computed inline.
    float* out = (float*)d_out;               // [B,S,NSTATE] fp32
    dim3 grid(4 * NH * (NQB / 2));            // 256 WGs, 1D for XCD co-location
    dim3 block(512);
    hipLaunchKernelGGL(mha_fwd, grid, block, 0, stream, x, out);
}